// Round 3
// baseline (518.945 us; speedup 1.0000x reference)
//
#include <hip/hip_runtime.h>

typedef _Float16 f16x8 __attribute__((ext_vector_type(8)));
typedef _Float16 f16x4 __attribute__((ext_vector_type(4)));
typedef float    f32x4 __attribute__((ext_vector_type(4)));

#define NH    12
#define HS    64
#define HID   768
#define EDIM  1536
#define NSEQ  1024
#define BSZ   8
#define MTOT  8192   // BSZ*NSEQ

// ---- workspace layout (bytes) ----
#define XH_OFF 0u                      // 8192*768*2   = 12582912
#define WT_OFF 12582912u               // 1536*768*2   =  2359296
#define QH_OFF 14942208u               // 8*12*1024*64*2 = 12582912
#define KH_OFF 27525120u               // same
#define CS_OFF 40108032u               // 1024*32*2*4 = 262144 (cos,sin interleaved)
// total end: 40370176

__device__ __forceinline__ void gl_lds16(const void* g, void* l) {
  __builtin_amdgcn_global_load_lds(
      (const __attribute__((address_space(1))) void*)g,
      (__attribute__((address_space(3))) void*)l, 16, 0, 0);
}

// ------------------------------------------------------------------
// prep: blocks [0,288): W -> W^T fp16 via LDS tile (coalesced both ways)
//       blocks [288,2048): x fp32->fp16 + fused cos/sin table [pos][32]
// ------------------------------------------------------------------
__global__ void prep_kernel(const float* __restrict__ x, const float* __restrict__ W,
                            _Float16* __restrict__ xh, _Float16* __restrict__ wt,
                            float* __restrict__ cst) {
  const int b = blockIdx.x;
  const int t = threadIdx.x;
  if (b < 288) {
    // 64(e) x 64(k) transpose tile; 24 e-tiles x 12 k-tiles
    __shared__ _Float16 lt[64][66];   // pad 66: write banks = el mod 32 (2-way, free)
    const int te = b % 24, tk = b / 24;
    const int e0t = te * 64, k0t = tk * 64;
#pragma unroll
    for (int i = 0; i < 16; ++i) {
      const int idx = i * 256 + t;
      const int kl = idx >> 6, el = idx & 63;      // consecutive t -> consecutive e (coalesced)
      lt[el][kl] = (_Float16)W[(size_t)(k0t + kl) * EDIM + e0t + el];
    }
    __syncthreads();
#pragma unroll
    for (int i = 0; i < 4; ++i) {
      const int idx = i * 256 + t;
      const int el = idx >> 4, kl4 = (idx & 15) * 4; // consecutive t -> consecutive k (coalesced 8B)
      f16x4 v;
      v.x = lt[el][kl4]; v.y = lt[el][kl4 + 1]; v.z = lt[el][kl4 + 2]; v.w = lt[el][kl4 + 3];
      *(f16x4*)&wt[(size_t)(e0t + el) * HID + k0t + kl4] = v;
    }
  } else {
    const int tid = (b - 288) * 256 + t;
    const int T = (gridDim.x - 288) * 256;
    const float4* x4 = (const float4*)x;
    f16x4* xh4 = (f16x4*)xh;
    for (int i = tid; i < (MTOT * HID / 4); i += T) {
      float4 v = x4[i];
      f16x4 h;
      h.x = (_Float16)v.x; h.y = (_Float16)v.y; h.z = (_Float16)v.z; h.w = (_Float16)v.w;
      xh4[i] = h;
    }
    for (int i = tid; i < NSEQ * 32; i += T) {
      const int pos = i >> 5, fi = i & 31;
      const float inv = powf(10000.0f, -(float)fi * (1.0f / 32.0f));
      const float ang = (float)pos * inv;
      cst[i * 2]     = cosf(ang);
      cst[i * 2 + 1] = sinf(ang);
    }
  }
}

// ------------------------------------------------------------------
// gemm1: proj = x @ W + b, fused interleaved RoPE, split q/k fp16 out
// 128x128 tile, BK=32, double-buffered LDS, ONE barrier per K-step.
// MFMA operands SWAPPED (mfma(W,x)): acc row = e-local, col = m-local.
// -> RoPE pair (e^1) is intra-thread (j^1), stores are f16x4.
// ------------------------------------------------------------------
__global__ __launch_bounds__(256, 2) void gemm1_kernel(
    const _Float16* __restrict__ xh, const _Float16* __restrict__ wt,
    const float* __restrict__ bias, const float* __restrict__ cst,
    _Float16* __restrict__ qh, _Float16* __restrict__ kh) {
  __shared__ __align__(16) _Float16 Ab[2][128 * 32];
  __shared__ __align__(16) _Float16 Bb[2][128 * 32];
  const int tid = threadIdx.x;
  const int w = tid >> 6, l = tid & 63;
  const int wm = w & 1, wn = w >> 1;
  const int m0 = blockIdx.x * 128, e0 = blockIdx.y * 128;

  // staging: chunk = 16B; row = 64B = 4 chunks; swizzle c_log = c_phys ^ (r&3) ^ ((r>>2)&3)
  const int rsub = l >> 2;                                  // row within 16-row chunk
  const int swz = (l & 3) ^ ((l >> 2) & 3) ^ (l >> 4);      // both c_log (staging) and phys (read)

  f32x4 acc[4][4] = {};

  auto stage = [&](int buf, int kt) {
#pragma unroll
    for (int j = 0; j < 2; ++j) {
      const int ch = w * 2 + j;
      gl_lds16(xh + (size_t)(m0 + ch * 16 + rsub) * HID + kt + swz * 8, &Ab[buf][ch * 512]);
      gl_lds16(wt + (size_t)(e0 + ch * 16 + rsub) * HID + kt + swz * 8, &Bb[buf][ch * 512]);
    }
  };

  auto compute = [&](int buf) {
    f16x8 af[4], bf[4];
#pragma unroll
    for (int mi = 0; mi < 4; ++mi)
      af[mi] = *(const f16x8*)&Ab[buf][(wm * 64 + mi * 16 + (l & 15)) * 32 + swz * 8];
#pragma unroll
    for (int ni = 0; ni < 4; ++ni)
      bf[ni] = *(const f16x8*)&Bb[buf][(wn * 64 + ni * 16 + (l & 15)) * 32 + swz * 8];
    // swapped: A-operand = W-frag, B-operand = x-frag
#pragma unroll
    for (int mi = 0; mi < 4; ++mi)
#pragma unroll
      for (int ni = 0; ni < 4; ++ni)
        acc[mi][ni] = __builtin_amdgcn_mfma_f32_16x16x32_f16(bf[ni], af[mi], acc[mi][ni], 0, 0, 0);
  };

  // prologue: fill buf 0
  stage(0, 0);
  __syncthreads();                 // vmcnt(0) drain + barrier: buf0 ready
  int cur = 0;
  for (int kt = 32; kt < HID; kt += 32) {
    stage(cur ^ 1, kt);            // prefetch next tile (in flight during MFMA)
    compute(cur);
    __syncthreads();               // drains prefetch; next buf ready; prev buf free
    cur ^= 1;
  }
  compute(cur);                    // last tile, no prefetch

  // epilogue: bias + RoPE, all intra-thread, vector loads/stores.
  // acc[mi][ni]: col(lane&15) = m-local (mi*16+..), row((l>>4)*4+j) = e-local (ni*16+..)
  const float2* cst2 = (const float2*)cst;
  const int hh = e0 >> 7;                       // head == blockIdx.y (128 cols per head)
#pragma unroll
  for (int mi = 0; mi < 4; ++mi) {
    const int m = m0 + wm * 64 + mi * 16 + (l & 15);
    const int bidx = m >> 10, pos = m & 1023;
    const float2* csrow = cst2 + pos * 32;
#pragma unroll
    for (int ni = 0; ni < 4; ++ni) {
      const int eb = wn * 64 + ni * 16 + ((l >> 4) << 2);   // e - e0, < 128, %4==0
      const int d = eb & 63;
      _Float16* const dst = (eb < 64) ? qh : kh;
      const float4 bv = *(const float4*)&bias[e0 + eb];
      const float2 cs0 = csrow[(d >> 1)];
      const float2 cs1 = csrow[(d >> 1) + 1];
      const float v0 = acc[mi][ni][0] + bv.x;
      const float v1 = acc[mi][ni][1] + bv.y;
      const float v2 = acc[mi][ni][2] + bv.z;
      const float v3 = acc[mi][ni][3] + bv.w;
      f16x4 o;
      o.x = (_Float16)(v0 * cs0.x - v1 * cs0.y);   // even e: v*cos - pair*sin
      o.y = (_Float16)(v1 * cs0.x + v0 * cs0.y);   // odd  e: v*cos + pair*sin
      o.z = (_Float16)(v2 * cs1.x - v3 * cs1.y);
      o.w = (_Float16)(v3 * cs1.x + v2 * cs1.y);
      *(f16x4*)&dst[(((size_t)bidx * NH + hh) * NSEQ + pos) * HS + d] = o;
    }
  }
}

// ------------------------------------------------------------------
// scores: per (b,h) S = Qr @ Kr^T, mask + causal + scale, fp32 out
// MFMA operands SWAPPED (mfma(K,Q)): acc row = n-local, col = m-local
// -> each thread owns 4 consecutive n => float4 stores (1KB/instr).
// ------------------------------------------------------------------
__global__ __launch_bounds__(256, 3) void scores_kernel(
    const _Float16* __restrict__ qh, const _Float16* __restrict__ kh,
    const float* __restrict__ mask, float* __restrict__ out) {
  __shared__ __align__(16) _Float16 Qb[128 * 64];
  __shared__ __align__(16) _Float16 Kb[128 * 64];
  const int tid = threadIdx.x;
  const int w = tid >> 6, l = tid & 63;
  const int wm = w & 1, wn = w >> 1;
  const int bh = blockIdx.z;
  const int bb = bh / NH;
  const int m0 = blockIdx.y * 128, n0 = blockIdx.x * 128;
  const _Float16* qbase = qh + (size_t)bh * NSEQ * HS + (size_t)m0 * HS;
  const _Float16* kbase = kh + (size_t)bh * NSEQ * HS + (size_t)n0 * HS;

  // staging: row = 128B = 8 chunks of 16B; swizzle c = s ^ (r&7)
#pragma unroll
  for (int j = 0; j < 4; ++j) {
    const int r = w * 32 + j * 8 + (l >> 3);
    const int c = (l & 7) ^ ((l >> 3) & 7);
    gl_lds16(qbase + r * 64 + c * 8, &Qb[w * 2048 + j * 512]);
    gl_lds16(kbase + r * 64 + c * 8, &Kb[w * 2048 + j * 512]);
  }
  __syncthreads();

  f32x4 acc[4][4] = {};
#pragma unroll
  for (int ks = 0; ks < 2; ++ks) {
    const int cl = ks * 4 + (l >> 4);
    f16x8 af[4], bf[4];
#pragma unroll
    for (int mi = 0; mi < 4; ++mi) {
      const int r = wm * 64 + mi * 16 + (l & 15);
      af[mi] = *(const f16x8*)&Qb[r * 64 + (cl ^ (l & 7)) * 8];
    }
#pragma unroll
    for (int ni = 0; ni < 4; ++ni) {
      const int r = wn * 64 + ni * 16 + (l & 15);
      bf[ni] = *(const f16x8*)&Kb[r * 64 + (cl ^ (l & 7)) * 8];
    }
    // swapped: A-operand = K-frag, B-operand = Q-frag
#pragma unroll
    for (int mi = 0; mi < 4; ++mi)
#pragma unroll
      for (int ni = 0; ni < 4; ++ni)
        acc[mi][ni] = __builtin_amdgcn_mfma_f32_16x16x32_f16(bf[ni], af[mi], acc[mi][ni], 0, 0, 0);
  }

  // acc[mi][ni]: col(lane&15) = m-local (mi*16+..), row((l>>4)*4+j) = n-local (ni*16+..)
  const float NEGC = 1000000000000.0f;
#pragma unroll
  for (int mi = 0; mi < 4; ++mi) {
    const int m = m0 + wm * 64 + mi * 16 + (l & 15);
    const float mq = mask[bb * NSEQ + m];
    const size_t rowbase = ((size_t)bh * NSEQ + m) * NSEQ;
#pragma unroll
    for (int ni = 0; ni < 4; ++ni) {
      const int nb = n0 + wn * 64 + ni * 16 + ((l >> 4) << 2);   // %4==0
      const float4 mk4 = *(const float4*)&mask[bb * NSEQ + nb];
      float mk[4] = {mk4.x, mk4.y, mk4.z, mk4.w};
      float4 o;
#pragma unroll
      for (int j = 0; j < 4; ++j) {
        float v = acc[mi][ni][j];
        v = v * mq + NEGC * (mq - 1.0f);
        v = v * mk[j] + NEGC * (mk[j] - 1.0f);
        if (nb + j < m) v -= NEGC;          // tril(k=-1): n < m masked
        (&o.x)[j] = v * 0.125f;             // 1/sqrt(64)
      }
      *(float4*)&out[rowbase + nb] = o;
    }
  }
}

extern "C" void kernel_launch(void* const* d_in, const int* in_sizes, int n_in,
                              void* d_out, int out_size, void* d_ws, size_t ws_size,
                              hipStream_t stream) {
  const float* x    = (const float*)d_in[0];
  const float* W    = (const float*)d_in[1];
  const float* bias = (const float*)d_in[2];
  const float* mask = (const float*)d_in[3];
  float* out = (float*)d_out;
  char* ws = (char*)d_ws;

  _Float16* xh = (_Float16*)(ws + XH_OFF);
  _Float16* wt = (_Float16*)(ws + WT_OFF);
  _Float16* qh = (_Float16*)(ws + QH_OFF);
  _Float16* kh = (_Float16*)(ws + KH_OFF);
  float* cst = (float*)(ws + CS_OFF);

  prep_kernel<<<2048, 256, 0, stream>>>(x, W, xh, wt, cst);

  dim3 g1(MTOT / 128, EDIM / 128);  // 64 x 12
  gemm1_kernel<<<g1, 256, 0, stream>>>(xh, wt, bias, cst, qh, kh);

  dim3 g2(NSEQ / 128, NSEQ / 128, BSZ * NH);  // 8 x 8 x 96
  scores_kernel<<<g2, 256, 0, stream>>>(qh, kh, mask, out);
}

// Round 4
// 454.920 us; speedup vs baseline: 1.1407x; 1.1407x over previous
//
#include <hip/hip_runtime.h>

typedef _Float16 f16x8 __attribute__((ext_vector_type(8)));
typedef _Float16 f16x4 __attribute__((ext_vector_type(4)));
typedef float    f32x4 __attribute__((ext_vector_type(4)));

#define NH    12
#define HS    64
#define HID   768
#define EDIM  1536
#define NSEQ  1024
#define BSZ   8
#define MTOT  8192   // BSZ*NSEQ

// ---- workspace layout (bytes) ----
#define XH_OFF 0u                      // 8192*768*2   = 12582912
#define WT_OFF 12582912u               // 1536*768*2   =  2359296
#define QH_OFF 14942208u               // 8*12*1024*64*2 = 12582912
#define KH_OFF 27525120u               // same
#define CS_OFF 40108032u               // 1024*32*2*4 = 262144 (cos,sin interleaved)
// total end: 40370176

__device__ __forceinline__ void gl_lds16(const void* g, void* l) {
  __builtin_amdgcn_global_load_lds(
      (const __attribute__((address_space(1))) void*)g,
      (__attribute__((address_space(3))) void*)l, 16, 0, 0);
}

// ------------------------------------------------------------------
// prep: blocks [0,288): W -> W^T fp16 via LDS tile (coalesced both ways)
//       blocks [288,2048): x fp32->fp16 + fused cos/sin table [pos][32]
// ------------------------------------------------------------------
__global__ void prep_kernel(const float* __restrict__ x, const float* __restrict__ W,
                            _Float16* __restrict__ xh, _Float16* __restrict__ wt,
                            float* __restrict__ cst) {
  const int b = blockIdx.x;
  const int t = threadIdx.x;
  if (b < 288) {
    // 64(e) x 64(k) transpose tile; 24 e-tiles x 12 k-tiles
    __shared__ _Float16 lt[64][66];   // pad 66: write banks = el mod 32 (2-way, free)
    const int te = b % 24, tk = b / 24;
    const int e0t = te * 64, k0t = tk * 64;
#pragma unroll
    for (int i = 0; i < 16; ++i) {
      const int idx = i * 256 + t;
      const int kl = idx >> 6, el = idx & 63;      // consecutive t -> consecutive e (coalesced)
      lt[el][kl] = (_Float16)W[(size_t)(k0t + kl) * EDIM + e0t + el];
    }
    __syncthreads();
#pragma unroll
    for (int i = 0; i < 4; ++i) {
      const int idx = i * 256 + t;
      const int el = idx >> 4, kl4 = (idx & 15) * 4; // consecutive t -> consecutive k (coalesced 8B)
      f16x4 v;
      v.x = lt[el][kl4]; v.y = lt[el][kl4 + 1]; v.z = lt[el][kl4 + 2]; v.w = lt[el][kl4 + 3];
      *(f16x4*)&wt[(size_t)(e0t + el) * HID + k0t + kl4] = v;
    }
  } else {
    const int tid = (b - 288) * 256 + t;
    const int T = (gridDim.x - 288) * 256;
    const float4* x4 = (const float4*)x;
    f16x4* xh4 = (f16x4*)xh;
    for (int i = tid; i < (MTOT * HID / 4); i += T) {
      float4 v = x4[i];
      f16x4 h;
      h.x = (_Float16)v.x; h.y = (_Float16)v.y; h.z = (_Float16)v.z; h.w = (_Float16)v.w;
      xh4[i] = h;
    }
    for (int i = tid; i < NSEQ * 32; i += T) {
      const int pos = i >> 5, fi = i & 31;
      const float inv = powf(10000.0f, -(float)fi * (1.0f / 32.0f));
      const float ang = (float)pos * inv;
      cst[i * 2]     = cosf(ang);
      cst[i * 2 + 1] = sinf(ang);
    }
  }
}

// ------------------------------------------------------------------
// gemm1: proj = x @ W + b, fused interleaved RoPE, split q/k fp16 out
// 128x128 tile, BK=32, double-buffered LDS (stage k+1 before compute k,
// ONE barrier per K-step), global_load_lds with XOR swizzle.
// ------------------------------------------------------------------
__global__ __launch_bounds__(256, 2) void gemm1_kernel(
    const _Float16* __restrict__ xh, const _Float16* __restrict__ wt,
    const float* __restrict__ bias, const float* __restrict__ cst,
    _Float16* __restrict__ qh, _Float16* __restrict__ kh) {
  __shared__ __align__(16) _Float16 Ab[2][128 * 32];
  __shared__ __align__(16) _Float16 Bb[2][128 * 32];
  const int tid = threadIdx.x;
  const int w = tid >> 6, l = tid & 63;
  const int wm = w & 1, wn = w >> 1;
  const int m0 = blockIdx.x * 128, e0 = blockIdx.y * 128;

  // staging: chunk = 16B; row = 64B = 4 chunks; swizzle c_log = c_phys ^ (r&3) ^ ((r>>2)&3)
  const int rsub = l >> 2;                                  // row within 16-row chunk
  const int swz = (l & 3) ^ ((l >> 2) & 3) ^ (l >> 4);      // both c_log (staging) and phys (read)

  f32x4 acc[4][4] = {};

  auto stage = [&](int buf, int kt) {
#pragma unroll
    for (int j = 0; j < 2; ++j) {
      const int ch = w * 2 + j;
      gl_lds16(xh + (size_t)(m0 + ch * 16 + rsub) * HID + kt + swz * 8, &Ab[buf][ch * 512]);
      gl_lds16(wt + (size_t)(e0 + ch * 16 + rsub) * HID + kt + swz * 8, &Bb[buf][ch * 512]);
    }
  };

  auto compute = [&](int buf) {
    f16x8 af[4], bf[4];
#pragma unroll
    for (int mi = 0; mi < 4; ++mi)
      af[mi] = *(const f16x8*)&Ab[buf][(wm * 64 + mi * 16 + (l & 15)) * 32 + swz * 8];
#pragma unroll
    for (int ni = 0; ni < 4; ++ni)
      bf[ni] = *(const f16x8*)&Bb[buf][(wn * 64 + ni * 16 + (l & 15)) * 32 + swz * 8];
#pragma unroll
    for (int mi = 0; mi < 4; ++mi)
#pragma unroll
      for (int ni = 0; ni < 4; ++ni)
        acc[mi][ni] = __builtin_amdgcn_mfma_f32_16x16x32_f16(af[mi], bf[ni], acc[mi][ni], 0, 0, 0);
  };

  // prologue: fill buf 0
  stage(0, 0);
  __syncthreads();                 // vmcnt(0) drain + barrier: buf0 ready
  int cur = 0;
  for (int kt = 32; kt < HID; kt += 32) {
    stage(cur ^ 1, kt);            // prefetch next tile (in flight during MFMA)
    compute(cur);
    __syncthreads();               // drains prefetch; next buf ready; prev buf free
    cur ^= 1;
  }
  compute(cur);                    // last tile, no prefetch

  // epilogue: bias + RoPE (pair value lives in adjacent lane: col = lane&15)
  const float2* cst2 = (const float2*)cst;
#pragma unroll
  for (int ni = 0; ni < 4; ++ni) {
    const int e = e0 + wn * 64 + ni * 16 + (l & 15);
    const float bv = bias[e];
    const int ia = (e & 63) >> 1;        // rope frequency index
    const int hh = e >> 7;               // head
    const int cc = e & 127;              // pos within head block (q:0-63, k:64-127)
    _Float16* const dst = (cc < 64) ? qh : kh;
    const int d = cc & 63;
    const float sgn = (e & 1) ? 1.0f : -1.0f;
#pragma unroll
    for (int mi = 0; mi < 4; ++mi) {
#pragma unroll
      for (int j = 0; j < 4; ++j) {
        const int m = m0 + wm * 64 + mi * 16 + ((l >> 4) << 2) + j;
        const int bidx = m >> 10;
        const int pos = m & 1023;
        float v = acc[mi][ni][j] + bv;
        float p = __shfl_xor(v, 1);      // value at e^1 (same row)
        const float2 cs = cst2[pos * 32 + ia];
        float ov = v * cs.x + sgn * p * cs.y;
        dst[(((size_t)bidx * NH + hh) * NSEQ + pos) * HS + d] = (_Float16)ov;
      }
    }
  }
}

// ------------------------------------------------------------------
// scores: per (b,h) S = Qr @ Kr^T, mask + causal + scale, fp32 out
// 128x128 tile, K=64 staged once (32 MFMAs), write-bound.
// SINGLE CHANGE vs round-1 measured-best: occupancy 2 -> 3 blocks/CU
// (more TLP to cover store drain; LDS 32KB*3 fits, VGPR fits 168 cap).
// ------------------------------------------------------------------
__global__ __launch_bounds__(256, 3) void scores_kernel(
    const _Float16* __restrict__ qh, const _Float16* __restrict__ kh,
    const float* __restrict__ mask, float* __restrict__ out) {
  __shared__ __align__(16) _Float16 Qb[128 * 64];
  __shared__ __align__(16) _Float16 Kb[128 * 64];
  const int tid = threadIdx.x;
  const int w = tid >> 6, l = tid & 63;
  const int wm = w & 1, wn = w >> 1;
  const int bh = blockIdx.z;
  const int bb = bh / NH;
  const int m0 = blockIdx.y * 128, n0 = blockIdx.x * 128;
  const _Float16* qbase = qh + (size_t)bh * NSEQ * HS + (size_t)m0 * HS;
  const _Float16* kbase = kh + (size_t)bh * NSEQ * HS + (size_t)n0 * HS;

  // staging: row = 128B = 8 chunks of 16B; swizzle c = s ^ (r&7)
#pragma unroll
  for (int j = 0; j < 4; ++j) {
    const int r = w * 32 + j * 8 + (l >> 3);
    const int c = (l & 7) ^ ((l >> 3) & 7);
    gl_lds16(qbase + r * 64 + c * 8, &Qb[w * 2048 + j * 512]);
    gl_lds16(kbase + r * 64 + c * 8, &Kb[w * 2048 + j * 512]);
  }
  __syncthreads();

  f32x4 acc[4][4] = {};
#pragma unroll
  for (int ks = 0; ks < 2; ++ks) {
    const int cl = ks * 4 + (l >> 4);
    f16x8 af[4], bf[4];
#pragma unroll
    for (int mi = 0; mi < 4; ++mi) {
      const int r = wm * 64 + mi * 16 + (l & 15);
      af[mi] = *(const f16x8*)&Qb[r * 64 + (cl ^ (l & 7)) * 8];
    }
#pragma unroll
    for (int ni = 0; ni < 4; ++ni) {
      const int r = wn * 64 + ni * 16 + (l & 15);
      bf[ni] = *(const f16x8*)&Kb[r * 64 + (cl ^ (l & 7)) * 8];
    }
#pragma unroll
    for (int mi = 0; mi < 4; ++mi)
#pragma unroll
      for (int ni = 0; ni < 4; ++ni)
        acc[mi][ni] = __builtin_amdgcn_mfma_f32_16x16x32_f16(af[mi], bf[ni], acc[mi][ni], 0, 0, 0);
  }

  const float NEGC = 1000000000000.0f;
  float mkv[4];
  int nn[4];
#pragma unroll
  for (int ni = 0; ni < 4; ++ni) {
    nn[ni] = n0 + wn * 64 + ni * 16 + (l & 15);
    mkv[ni] = mask[bb * NSEQ + nn[ni]];
  }
#pragma unroll
  for (int mi = 0; mi < 4; ++mi) {
#pragma unroll
    for (int j = 0; j < 4; ++j) {
      const int m = m0 + wm * 64 + mi * 16 + ((l >> 4) << 2) + j;
      const float mq = mask[bb * NSEQ + m];
      const size_t rowbase = ((size_t)bh * NSEQ + m) * NSEQ;
#pragma unroll
      for (int ni = 0; ni < 4; ++ni) {
        float v = acc[mi][ni][j];
        v = v * mq + NEGC * (mq - 1.0f);
        v = v * mkv[ni] + NEGC * (mkv[ni] - 1.0f);
        if (nn[ni] < m) v -= NEGC;          // tril(k=-1): n < m masked
        out[rowbase + nn[ni]] = v * 0.125f; // 1/sqrt(64)
      }
    }
  }
}

extern "C" void kernel_launch(void* const* d_in, const int* in_sizes, int n_in,
                              void* d_out, int out_size, void* d_ws, size_t ws_size,
                              hipStream_t stream) {
  const float* x    = (const float*)d_in[0];
  const float* W    = (const float*)d_in[1];
  const float* bias = (const float*)d_in[2];
  const float* mask = (const float*)d_in[3];
  float* out = (float*)d_out;
  char* ws = (char*)d_ws;

  _Float16* xh = (_Float16*)(ws + XH_OFF);
  _Float16* wt = (_Float16*)(ws + WT_OFF);
  _Float16* qh = (_Float16*)(ws + QH_OFF);
  _Float16* kh = (_Float16*)(ws + KH_OFF);
  float* cst = (float*)(ws + CS_OFF);

  prep_kernel<<<2048, 256, 0, stream>>>(x, W, xh, wt, cst);

  dim3 g1(MTOT / 128, EDIM / 128);  // 64 x 12
  gemm1_kernel<<<g1, 256, 0, stream>>>(xh, wt, bias, cst, qh, kh);

  dim3 g2(NSEQ / 128, NSEQ / 128, BSZ * NH);  // 8 x 8 x 96
  scores_kernel<<<g2, 256, 0, stream>>>(qh, kh, mask, out);
}